// Round 1
// baseline (797.838 us; speedup 1.0000x reference)
//
#include <hip/hip_runtime.h>
#include <hip/hip_bf16.h>
#include <cstddef>

// ---------------------------------------------------------------------------
// CustomMultiheadAttention: S=2048, E=1024, H=16, HD=64, P=64
// out = (attn @ Wo^T + bo, w) ; w = softmax((q k^T + sim sim^T) * 1/8)
//
// Pipeline:
//   1. k_cvt_sim: sim -> bf16 hi/lo split (hi + lo == sim to ~2^-18)
//   2. k_gemm_qkv: q/k/v projections (bf16 MFMA, f32 acc); q,k stored
//      [H][S][HD] bf16, v stored transposed [H][HD][S] bf16
//   3. k_attn: per (head, 64 q-rows) block, 4 independent waves x 16 rows.
//      Two sweeps over t: (a) online max/sumexp, (b) recompute scores,
//      write w (f32, LDS-coalesced), PV accumulate via LDS transpose.
//      scores = q.k + sim_hi.sim_hi + sim_lo.sim_hi + sim_hi.sim_lo (K=256)
//   4. k_gemm_out: out = attn @ Wo^T + bo (f32 out to d_out[0:S*E])
// ---------------------------------------------------------------------------

#define S 2048
#define E 1024
#define H 16
#define HD 64
#define PD 64
#define SCALE 0.125f

typedef __bf16 bf16x8 __attribute__((ext_vector_type(8)));
typedef __bf16 bf16x4 __attribute__((ext_vector_type(4)));
typedef float f32x4 __attribute__((ext_vector_type(4)));

#define MFMA16(a, b, c) __builtin_amdgcn_mfma_f32_16x16x32_bf16((a), (b), (c), 0, 0, 0)

// ---------------------------------------------------------------------------
// sim -> bf16 hi/lo split
__global__ __launch_bounds__(256) void k_cvt_sim(const float* __restrict__ sim,
                                                 __bf16* __restrict__ hi,
                                                 __bf16* __restrict__ lo) {
    int i = blockIdx.x * 256 + threadIdx.x;  // total S*PD = 131072
    float x = sim[i];
    __bf16 h = (__bf16)x;
    hi[i] = h;
    lo[i] = (__bf16)(x - (float)h);
}

// ---------------------------------------------------------------------------
// Generic 128x128-tile GEMM: C[M=2048][N=1024] = A[2048][1024] * Bm[1024][1024]^T + bias
// mode 0: f32 out[row*1024+col]
// mode 1: bf16 out[(col/64)*S*64 + row*64 + (col&63)]        ([H][S][HD])
// mode 2: bf16 out[((col/64)*64 + (col&63))*S + row]          ([H][HD][S])
__device__ __forceinline__ void gemm128_core(const float* __restrict__ A,
                                             const float* __restrict__ Bm,
                                             const float* __restrict__ bias,
                                             float* __restrict__ outf,
                                             __bf16* __restrict__ outb, int mode) {
    const int K = 1024;
    __shared__ __bf16 As[128][40];  // 80 B stride: 16B-aligned rows, ~2-way banks
    __shared__ __bf16 Bs[128][40];
    const int tid = threadIdx.x;
    const int lane = tid & 63, wid = tid >> 6;
    const int l15 = lane & 15, g = lane >> 4;
    const int m0 = blockIdx.y * 128, n0 = blockIdx.x * 128;
    const int wrow = (wid >> 1) * 64, wcol = (wid & 1) * 64;

    f32x4 acc[4][4] = {};

    for (int ks = 0; ks < K; ks += 32) {
        __syncthreads();
#pragma unroll
        for (int i = 0; i < 4; ++i) {
            int idx = i * 256 + tid;
            int row = idx >> 3, kc = (idx & 7) * 4;
            float4 av = *(const float4*)(A + (size_t)(m0 + row) * K + ks + kc);
            float4 bv = *(const float4*)(Bm + (size_t)(n0 + row) * K + ks + kc);
            bf16x4 a4 = {(__bf16)av.x, (__bf16)av.y, (__bf16)av.z, (__bf16)av.w};
            bf16x4 b4 = {(__bf16)bv.x, (__bf16)bv.y, (__bf16)bv.z, (__bf16)bv.w};
            *(bf16x4*)&As[row][kc] = a4;
            *(bf16x4*)&Bs[row][kc] = b4;
        }
        __syncthreads();
        bf16x8 af[4], bfr[4];
#pragma unroll
        for (int mi = 0; mi < 4; ++mi)
            af[mi] = *(const bf16x8*)&As[wrow + mi * 16 + l15][g * 8];
#pragma unroll
        for (int ni = 0; ni < 4; ++ni)
            bfr[ni] = *(const bf16x8*)&Bs[wcol + ni * 16 + l15][g * 8];
#pragma unroll
        for (int mi = 0; mi < 4; ++mi)
#pragma unroll
            for (int ni = 0; ni < 4; ++ni)
                acc[mi][ni] = MFMA16(af[mi], bfr[ni], acc[mi][ni]);
    }

#pragma unroll
    for (int ni = 0; ni < 4; ++ni) {
        int col = n0 + wcol + ni * 16 + l15;
        float bv = bias[col];
#pragma unroll
        for (int mi = 0; mi < 4; ++mi) {
            int row = m0 + wrow + mi * 16 + g * 4;
#pragma unroll
            for (int r = 0; r < 4; ++r) {
                float v = acc[mi][ni][r] + bv;
                if (mode == 0) {
                    outf[(size_t)(row + r) * 1024 + col] = v;
                } else if (mode == 1) {
                    outb[(((size_t)(col >> 6)) * S + row + r) * 64 + (col & 63)] = (__bf16)v;
                } else {
                    outb[(((size_t)(col >> 6)) * 64 + (col & 63)) * S + row + r] = (__bf16)v;
                }
            }
        }
    }
}

__global__ __launch_bounds__(256) void k_gemm_qkv(
    const float* __restrict__ q, const float* __restrict__ k, const float* __restrict__ v,
    const float* __restrict__ Wq, const float* __restrict__ Wk, const float* __restrict__ Wv,
    const float* __restrict__ bq, const float* __restrict__ bk, const float* __restrict__ bv,
    __bf16* __restrict__ qo, __bf16* __restrict__ ko, __bf16* __restrict__ vto) {
    int z = blockIdx.z;
    const float* A = z == 0 ? q : (z == 1 ? k : v);
    const float* W = z == 0 ? Wq : (z == 1 ? Wk : Wv);
    const float* b = z == 0 ? bq : (z == 1 ? bk : bv);
    __bf16* ob = z == 0 ? qo : (z == 1 ? ko : vto);
    gemm128_core(A, W, b, nullptr, ob, z == 2 ? 2 : 1);
}

__global__ __launch_bounds__(256) void k_gemm_out(const float* __restrict__ A,
                                                  const float* __restrict__ W,
                                                  const float* __restrict__ b,
                                                  float* __restrict__ out) {
    gemm128_core(A, W, b, out, nullptr, 0);
}

// ---------------------------------------------------------------------------
// Attention
struct QFrags {
    bf16x8 q0, q1, h0, h1, l0, l1;
};

__device__ __forceinline__ f32x4 score_tile(const QFrags& A, const __bf16* __restrict__ kb,
                                            const __bf16* __restrict__ shi,
                                            const __bf16* __restrict__ slo, int h, int tb,
                                            int l15, int g) {
    const __bf16* krow = kb + ((size_t)h * S + tb + l15) * HD + g * 8;
    const __bf16* hrow = shi + (size_t)(tb + l15) * PD + g * 8;
    const __bf16* lrow = slo + (size_t)(tb + l15) * PD + g * 8;
    f32x4 sc = {};
    sc = MFMA16(A.q0, *(const bf16x8*)(krow), sc);
    sc = MFMA16(A.q1, *(const bf16x8*)(krow + 32), sc);
    bf16x8 bh0 = *(const bf16x8*)(hrow);
    bf16x8 bh1 = *(const bf16x8*)(hrow + 32);
    sc = MFMA16(A.h0, bh0, sc);
    sc = MFMA16(A.h1, bh1, sc);
    sc = MFMA16(A.l0, bh0, sc);
    sc = MFMA16(A.l1, bh1, sc);
    sc = MFMA16(A.h0, *(const bf16x8*)(lrow), sc);
    sc = MFMA16(A.h1, *(const bf16x8*)(lrow + 32), sc);
    return sc;
}

__global__ __launch_bounds__(256) void k_attn(
    const __bf16* __restrict__ qb, const __bf16* __restrict__ kb,
    const __bf16* __restrict__ vtb, const __bf16* __restrict__ shi,
    const __bf16* __restrict__ slo, float* __restrict__ w_out,
    float* __restrict__ attn_out) {
    const int h = blockIdx.y;
    const int tid = threadIdx.x;
    const int lane = tid & 63, wid = tid >> 6;
    const int l15 = lane & 15, g = lane >> 4;
    const int s0 = blockIdx.x * 64 + wid * 16;

    __shared__ float lds_w[4][16][36];
    float(*wt)[36] = lds_w[wid];

    QFrags A;
    {
        const __bf16* qrow = qb + ((size_t)h * S + s0 + l15) * HD;
        A.q0 = *(const bf16x8*)(qrow + g * 8);
        A.q1 = *(const bf16x8*)(qrow + 32 + g * 8);
        const __bf16* hr = shi + (size_t)(s0 + l15) * PD;
        A.h0 = *(const bf16x8*)(hr + g * 8);
        A.h1 = *(const bf16x8*)(hr + 32 + g * 8);
        const __bf16* lr = slo + (size_t)(s0 + l15) * PD;
        A.l0 = *(const bf16x8*)(lr + g * 8);
        A.l1 = *(const bf16x8*)(lr + 32 + g * 8);
    }

    float m[4] = {-1e30f, -1e30f, -1e30f, -1e30f};
    float lsum[4] = {0.f, 0.f, 0.f, 0.f};

    // sweep 1: online row max + sumexp
#pragma unroll 1
    for (int t0 = 0; t0 < S; t0 += 32) {
        float val[2][4];
#pragma unroll
        for (int tt = 0; tt < 2; ++tt) {
            f32x4 sc = score_tile(A, kb, shi, slo, h, t0 + tt * 16, l15, g);
#pragma unroll
            for (int r = 0; r < 4; ++r) val[tt][r] = sc[r] * SCALE;
        }
#pragma unroll
        for (int r = 0; r < 4; ++r) {
            float tmax = fmaxf(val[0][r], val[1][r]);
#pragma unroll
            for (int o = 8; o > 0; o >>= 1) tmax = fmaxf(tmax, __shfl_xor(tmax, o));
            float mn = fmaxf(m[r], tmax);
            float p = __expf(val[0][r] - mn) + __expf(val[1][r] - mn);
#pragma unroll
            for (int o = 8; o > 0; o >>= 1) p += __shfl_xor(p, o);
            lsum[r] = lsum[r] * __expf(m[r] - mn) + p;
            m[r] = mn;
        }
    }
    float rinv[4];
#pragma unroll
    for (int r = 0; r < 4; ++r) rinv[r] = 1.0f / lsum[r];

    f32x4 acc[4] = {};

    // sweep 2: recompute scores, emit w, accumulate PV
#pragma unroll 1
    for (int t0 = 0; t0 < S; t0 += 32) {
#pragma unroll
        for (int tt = 0; tt < 2; ++tt) {
            f32x4 sc = score_tile(A, kb, shi, slo, h, t0 + tt * 16, l15, g);
#pragma unroll
            for (int r = 0; r < 4; ++r) {
                float w = __expf(sc[r] * SCALE - m[r]) * rinv[r];
                wt[g * 4 + r][tt * 16 + l15] = w;
            }
        }
        // coalesced w write: 16 rows x 32 cols from LDS (128 B per row segment)
#pragma unroll
        for (int half = 0; half < 2; ++half) {
            int row = half * 8 + (lane >> 3);
            int cg = (lane & 7) * 4;
            float4 wv = *(const float4*)&wt[row][cg];
            *(float4*)&w_out[((size_t)h * S + s0 + row) * S + t0 + cg] = wv;
        }
        // PV: transpose via LDS -> A-frag (rows=s, k=t), B from v^T
        f32x4 wa = *(const f32x4*)&wt[l15][g * 8];
        f32x4 wb2 = *(const f32x4*)&wt[l15][g * 8 + 4];
        bf16x8 pa;
        pa[0] = (__bf16)wa[0]; pa[1] = (__bf16)wa[1];
        pa[2] = (__bf16)wa[2]; pa[3] = (__bf16)wa[3];
        pa[4] = (__bf16)wb2[0]; pa[5] = (__bf16)wb2[1];
        pa[6] = (__bf16)wb2[2]; pa[7] = (__bf16)wb2[3];
#pragma unroll
        for (int dt = 0; dt < 4; ++dt) {
            const __bf16* vrow = vtb + ((size_t)h * HD + dt * 16 + l15) * S + t0 + g * 8;
            acc[dt] = MFMA16(pa, *(const bf16x8*)vrow, acc[dt]);
        }
    }

    // epilogue: attn_out[s][h*64 + d]
#pragma unroll
    for (int dt = 0; dt < 4; ++dt)
#pragma unroll
        for (int r = 0; r < 4; ++r)
            attn_out[(size_t)(s0 + g * 4 + r) * E + h * 64 + dt * 16 + l15] = acc[dt][r];
}

// ---------------------------------------------------------------------------
extern "C" void kernel_launch(void* const* d_in, const int* in_sizes, int n_in,
                              void* d_out, int out_size, void* d_ws, size_t ws_size,
                              hipStream_t stream) {
    (void)in_sizes; (void)n_in; (void)out_size; (void)ws_size;
    const float* query = (const float*)d_in[0];
    const float* key   = (const float*)d_in[1];
    const float* value = (const float*)d_in[2];
    const float* sim   = (const float*)d_in[3];
    const float* Wq = (const float*)d_in[4];
    const float* bq = (const float*)d_in[5];
    const float* Wk = (const float*)d_in[6];
    const float* bk = (const float*)d_in[7];
    const float* Wv = (const float*)d_in[8];
    const float* bv = (const float*)d_in[9];
    const float* Wo = (const float*)d_in[10];
    const float* bo = (const float*)d_in[11];

    char* ws = (char*)d_ws;
    __bf16* q_bf  = (__bf16*)(ws);                        // 4 MB  [H][S][HD]
    __bf16* k_bf  = (__bf16*)(ws + (4u << 20));           // 4 MB  [H][S][HD]
    __bf16* vt_bf = (__bf16*)(ws + (8u << 20));           // 4 MB  [H][HD][S]
    __bf16* s_hi  = (__bf16*)(ws + (12u << 20));          // 256 KB [S][PD]
    __bf16* s_lo  = (__bf16*)(ws + (12u << 20) + (1u << 18));
    float*  attn_f = (float*)(ws + (12u << 20) + (1u << 19));  // 8 MB [S][E]

    float* out_f = (float*)d_out;                 // [S][E]
    float* w_out = out_f + (size_t)S * E;         // [H][S][S]

    k_cvt_sim<<<dim3((S * PD) / 256), dim3(256), 0, stream>>>(sim, s_hi, s_lo);
    k_gemm_qkv<<<dim3(8, 16, 3), dim3(256), 0, stream>>>(
        query, key, value, Wq, Wk, Wv, bq, bk, bv, q_bf, k_bf, vt_bf);
    k_attn<<<dim3(S / 64, H), dim3(256), 0, stream>>>(
        q_bf, k_bf, vt_bf, s_hi, s_lo, w_out, attn_f);
    k_gemm_out<<<dim3(8, 16, 1), dim3(256), 0, stream>>>(attn_f, Wo, bo, out_f);
}

// Round 3
// 574.026 us; speedup vs baseline: 1.3899x; 1.3899x over previous
//
#include <hip/hip_runtime.h>
#include <hip/hip_bf16.h>
#include <cstddef>

// ---------------------------------------------------------------------------
// CustomMultiheadAttention: S=2048, E=1024, H=16, HD=64, P=64
//   out = (attn @ Wo^T + bo, w);  w = softmax((q k^T + sim sim^T) / 8)
//
// Round-2 structure (fixes round-1 latency-bound attention: occ 23%, 2 w/SIMD):
//   1. k_rel: rel_s[S][S] f32 = (sim sim^T)/8, exact f32 VALU GEMM (K=64)
//   2. k_gemm_qkv: projections via bf16 MFMA, BK=64; q pre-scaled by 1/8;
//      q,k,v stored [H][S][64] bf16
//   3. k_tr_v: v -> v^T [H][HD][S] (LDS transpose, coalesced both sides)
//   4. k_stats (grid x4 t-chunks, 32 waves/CU): row sums of exp(score),
//      score = MFMA(q,k) seeded with rel_s (2-deep chain). No max
//      subtraction: |score| <= ~8 << 88, exp cannot overflow f32.
//   5. k_combine: rinv = 1/sum of chunk partials
//   6. k_emit (grid x4): recompute scores, w = exp(s)*rinv -> d_out (LDS-
//      staged float4 stores), PV via LDS transpose, atomicAdd f32 into attn_f
//   7. k_gemm_out: out = attn @ Wo^T + bo
// ---------------------------------------------------------------------------

#define S 2048
#define E 1024
#define H 16
#define HD 64
#define PD 64
#define NC 4
#define TC (S / NC)
#define SCALE 0.125f

typedef __bf16 bf16x8 __attribute__((ext_vector_type(8)));
typedef __bf16 bf16x4 __attribute__((ext_vector_type(4)));
typedef float f32x4 __attribute__((ext_vector_type(4)));

#define MFMA16(a, b, c) __builtin_amdgcn_mfma_f32_16x16x32_bf16((a), (b), (c), 0, 0, 0)

// ---------------------------------------------------------------------------
// rel_s = (sim sim^T) * 1/8, exact f32. 128x128 tile / block, K=64 in 2 chunks.
__global__ __launch_bounds__(256) void k_rel(const float* __restrict__ sim,
                                             float* __restrict__ rel) {
    __shared__ float As[128][33];
    __shared__ float Bs[128][33];
    const int tid = threadIdx.x;
    const int tx = tid & 15, ty = tid >> 4;
    const int m0 = blockIdx.y * 128, n0 = blockIdx.x * 128;
    float acc[8][8] = {};
#pragma unroll
    for (int kc = 0; kc < 2; ++kc) {
        __syncthreads();
#pragma unroll
        for (int i = 0; i < 4; ++i) {
            int fi = i * 256 + tid;               // 0..1023
            int row = fi >> 3, c4 = (fi & 7) * 4;
            float4 av = *(const float4*)(sim + (size_t)(m0 + row) * PD + kc * 32 + c4);
            float4 bv = *(const float4*)(sim + (size_t)(n0 + row) * PD + kc * 32 + c4);
            As[row][c4] = av.x; As[row][c4 + 1] = av.y; As[row][c4 + 2] = av.z; As[row][c4 + 3] = av.w;
            Bs[row][c4] = bv.x; Bs[row][c4 + 1] = bv.y; Bs[row][c4 + 2] = bv.z; Bs[row][c4 + 3] = bv.w;
        }
        __syncthreads();
        for (int k = 0; k < 32; ++k) {
            float a[8], b[8];
#pragma unroll
            for (int i = 0; i < 8; ++i) a[i] = As[ty * 8 + i][k];
#pragma unroll
            for (int j = 0; j < 8; ++j) b[j] = Bs[tx + 16 * j][k];
#pragma unroll
            for (int i = 0; i < 8; ++i)
#pragma unroll
                for (int j = 0; j < 8; ++j) acc[i][j] = fmaf(a[i], b[j], acc[i][j]);
        }
    }
#pragma unroll
    for (int i = 0; i < 8; ++i)
#pragma unroll
        for (int j = 0; j < 8; ++j)
            rel[(size_t)(m0 + ty * 8 + i) * S + n0 + tx + 16 * j] = acc[i][j] * SCALE;
}

// ---------------------------------------------------------------------------
// 128x128-tile GEMM, C = A[2048][1024] * Bm[1024][1024]^T + bias, BK=64.
// mode 0: f32 out[row*E+col] ; mode 1: bf16 out[((col>>6)*S + row)*64 + (col&63)]
__device__ __forceinline__ void gemm_core(const float* __restrict__ A,
                                          const float* __restrict__ Bm,
                                          const float* __restrict__ bias, float oscale,
                                          float* __restrict__ outf,
                                          __bf16* __restrict__ outb, int mode) {
    const int K = 1024;
    __shared__ __bf16 As[128][72];   // 144 B row stride: 16B-aligned, ~2-way banks
    __shared__ __bf16 Bs[128][72];
    const int tid = threadIdx.x;
    const int lane = tid & 63, wid = tid >> 6;
    const int l15 = lane & 15, g = lane >> 4;
    const int m0 = blockIdx.y * 128, n0 = blockIdx.x * 128;
    const int wrow = (wid >> 1) * 64, wcol = (wid & 1) * 64;

    f32x4 acc[4][4] = {};

    for (int ks = 0; ks < K; ks += 64) {
        __syncthreads();
#pragma unroll
        for (int i = 0; i < 8; ++i) {
            int fi = i * 256 + tid;               // 0..2047 float4 slots
            int row = fi >> 4, c4 = (fi & 15) * 4;
            float4 av = *(const float4*)(A + (size_t)(m0 + row) * K + ks + c4);
            float4 bv = *(const float4*)(Bm + (size_t)(n0 + row) * K + ks + c4);
            bf16x4 a4 = {(__bf16)av.x, (__bf16)av.y, (__bf16)av.z, (__bf16)av.w};
            bf16x4 b4 = {(__bf16)bv.x, (__bf16)bv.y, (__bf16)bv.z, (__bf16)bv.w};
            *(bf16x4*)&As[row][c4] = a4;
            *(bf16x4*)&Bs[row][c4] = b4;
        }
        __syncthreads();
#pragma unroll
        for (int half = 0; half < 2; ++half) {
            bf16x8 af[4], bfr[4];
#pragma unroll
            for (int mi = 0; mi < 4; ++mi)
                af[mi] = *(const bf16x8*)&As[wrow + mi * 16 + l15][half * 32 + g * 8];
#pragma unroll
            for (int ni = 0; ni < 4; ++ni)
                bfr[ni] = *(const bf16x8*)&Bs[wcol + ni * 16 + l15][half * 32 + g * 8];
#pragma unroll
            for (int mi = 0; mi < 4; ++mi)
#pragma unroll
                for (int ni = 0; ni < 4; ++ni)
                    acc[mi][ni] = MFMA16(af[mi], bfr[ni], acc[mi][ni]);
        }
    }

#pragma unroll
    for (int ni = 0; ni < 4; ++ni) {
        int col = n0 + wcol + ni * 16 + l15;
        float bv = bias[col];
#pragma unroll
        for (int mi = 0; mi < 4; ++mi) {
            int row = m0 + wrow + mi * 16 + g * 4;
#pragma unroll
            for (int r = 0; r < 4; ++r) {
                float v = (acc[mi][ni][r] + bv) * oscale;
                if (mode == 0)
                    outf[(size_t)(row + r) * E + col] = v;
                else
                    outb[(((size_t)(col >> 6)) * S + row + r) * HD + (col & 63)] = (__bf16)v;
            }
        }
    }
}

__global__ __launch_bounds__(256) void k_gemm_qkv(
    const float* __restrict__ q, const float* __restrict__ k, const float* __restrict__ v,
    const float* __restrict__ Wq, const float* __restrict__ Wk, const float* __restrict__ Wv,
    const float* __restrict__ bq, const float* __restrict__ bk, const float* __restrict__ bv,
    __bf16* __restrict__ qo, __bf16* __restrict__ ko, __bf16* __restrict__ vo) {
    int z = blockIdx.z;
    const float* A = z == 0 ? q : (z == 1 ? k : v);
    const float* W = z == 0 ? Wq : (z == 1 ? Wk : Wv);
    const float* b = z == 0 ? bq : (z == 1 ? bk : bv);
    __bf16* ob = z == 0 ? qo : (z == 1 ? ko : vo);
    gemm_core(A, W, b, z == 0 ? SCALE : 1.0f, nullptr, ob, 1);
}

__global__ __launch_bounds__(256) void k_gemm_out(const float* __restrict__ A,
                                                  const float* __restrict__ W,
                                                  const float* __restrict__ b,
                                                  float* __restrict__ out) {
    gemm_core(A, W, b, 1.0f, out, nullptr, 0);
}

// ---------------------------------------------------------------------------
// v [H][S][64] -> v^T [H][HD][S], 64x64 tiles
__global__ __launch_bounds__(256) void k_tr_v(const __bf16* __restrict__ vb,
                                              __bf16* __restrict__ vt) {
    __shared__ __bf16 t[64][72];
    const int h = blockIdx.y, s0 = blockIdx.x * 64, tid = threadIdx.x;
#pragma unroll
    for (int i = 0; i < 2; ++i) {
        int fi = i * 256 + tid;                   // 0..511
        int row = fi >> 3, c8 = (fi & 7) * 8;
        *(bf16x8*)&t[row][c8] = *(const bf16x8*)(vb + ((size_t)h * S + s0 + row) * HD + c8);
    }
    __syncthreads();
#pragma unroll
    for (int i = 0; i < 2; ++i) {
        int fi = i * 256 + tid;
        int d = fi >> 3, s8 = (fi & 7) * 8;
        bf16x8 o;
#pragma unroll
        for (int j = 0; j < 8; ++j) o[j] = t[s8 + j][d];
        *(bf16x8*)(vt + ((size_t)h * HD + d) * S + s0 + s8) = o;
    }
}

// ---------------------------------------------------------------------------
// stats: per-row sum of exp(score) over this block's t-chunk
__global__ __launch_bounds__(256) void k_stats(const __bf16* __restrict__ qb,
                                               const __bf16* __restrict__ kb,
                                               const float* __restrict__ rel,
                                               float* __restrict__ pst) {
    const int h = blockIdx.y, c = blockIdx.z;
    const int tid = threadIdx.x, lane = tid & 63, wid = tid >> 6;
    const int l15 = lane & 15, g = lane >> 4;
    const int srow = blockIdx.x * 64 + wid * 16;
    const __bf16* qr = qb + ((size_t)h * S + srow + l15) * HD + g * 8;
    bf16x8 q0 = *(const bf16x8*)qr;
    bf16x8 q1 = *(const bf16x8*)(qr + 32);
    const int r0 = srow + g * 4;
    const float* relbase = rel + (size_t)r0 * S;
    float lsum[4] = {0.f, 0.f, 0.f, 0.f};
#pragma unroll 1
    for (int tb = c * TC; tb < (c + 1) * TC; tb += 16) {
        f32x4 sc;
        const float* rp = relbase + tb + l15;
        sc[0] = rp[0]; sc[1] = rp[S]; sc[2] = rp[2 * S]; sc[3] = rp[3 * S];
        const __bf16* kr = kb + ((size_t)h * S + tb + l15) * HD + g * 8;
        sc = MFMA16(q0, *(const bf16x8*)kr, sc);
        sc = MFMA16(q1, *(const bf16x8*)(kr + 32), sc);
#pragma unroll
        for (int r = 0; r < 4; ++r) lsum[r] += __expf(sc[r]);
    }
#pragma unroll
    for (int r = 0; r < 4; ++r) {
#pragma unroll
        for (int o = 8; o > 0; o >>= 1) lsum[r] += __shfl_xor(lsum[r], o);
    }
    if (l15 == 0) {
#pragma unroll
        for (int r = 0; r < 4; ++r) pst[((size_t)c * H + h) * S + r0 + r] = lsum[r];
    }
}

__global__ __launch_bounds__(256) void k_combine(const float* __restrict__ pst,
                                                 float* __restrict__ rinv) {
    int i = blockIdx.x * 256 + threadIdx.x;       // H*S = 32768
    float L = 0.f;
#pragma unroll
    for (int c = 0; c < NC; ++c) L += pst[(size_t)c * H * S + i];
    rinv[i] = 1.0f / L;
}

// ---------------------------------------------------------------------------
// emit: recompute scores, write w, PV-accumulate (atomicAdd into attn)
__global__ __launch_bounds__(256) void k_emit(const __bf16* __restrict__ qb,
                                              const __bf16* __restrict__ kb,
                                              const __bf16* __restrict__ vt,
                                              const float* __restrict__ rel,
                                              const float* __restrict__ rinvv,
                                              float* __restrict__ w_out,
                                              float* __restrict__ attn) {
    __shared__ float lds_w[4][16][36];
    const int h = blockIdx.y, c = blockIdx.z;
    const int tid = threadIdx.x, lane = tid & 63, wid = tid >> 6;
    const int l15 = lane & 15, g = lane >> 4;
    const int srow = blockIdx.x * 64 + wid * 16;
    float(*wt)[36] = lds_w[wid];
    const __bf16* qr = qb + ((size_t)h * S + srow + l15) * HD + g * 8;
    bf16x8 q0 = *(const bf16x8*)qr;
    bf16x8 q1 = *(const bf16x8*)(qr + 32);
    const int r0 = srow + g * 4;
    float rin[4];
#pragma unroll
    for (int r = 0; r < 4; ++r) rin[r] = rinvv[h * S + r0 + r];
    const float* relbase = rel + (size_t)r0 * S;
    f32x4 acc[4] = {};

#pragma unroll 1
    for (int t0 = c * TC; t0 < (c + 1) * TC; t0 += 32) {
#pragma unroll
        for (int tt = 0; tt < 2; ++tt) {
            int tb = t0 + tt * 16;
            f32x4 sc;
            const float* rp = relbase + tb + l15;
            sc[0] = rp[0]; sc[1] = rp[S]; sc[2] = rp[2 * S]; sc[3] = rp[3 * S];
            const __bf16* kr = kb + ((size_t)h * S + tb + l15) * HD + g * 8;
            sc = MFMA16(q0, *(const bf16x8*)kr, sc);
            sc = MFMA16(q1, *(const bf16x8*)(kr + 32), sc);
#pragma unroll
            for (int r = 0; r < 4; ++r) wt[g * 4 + r][tt * 16 + l15] = __expf(sc[r]) * rin[r];
        }
        // coalesced w write: 16 rows x 32 cols (128 B per 8-lane group)
#pragma unroll
        for (int hf = 0; hf < 2; ++hf) {
            int row = hf * 8 + (lane >> 3);
            int cg = (lane & 7) * 4;
            float4 wv = *(const float4*)&wt[row][cg];
            *(float4*)&w_out[((size_t)h * S + srow + row) * S + t0 + cg] = wv;
        }
        // PV: A-frag = w rows via LDS transpose, B-frag from v^T
        f32x4 wa = *(const f32x4*)&wt[l15][g * 8];
        f32x4 wb = *(const f32x4*)&wt[l15][g * 8 + 4];
        bf16x8 pa;
        pa[0] = (__bf16)wa[0]; pa[1] = (__bf16)wa[1]; pa[2] = (__bf16)wa[2]; pa[3] = (__bf16)wa[3];
        pa[4] = (__bf16)wb[0]; pa[5] = (__bf16)wb[1]; pa[6] = (__bf16)wb[2]; pa[7] = (__bf16)wb[3];
#pragma unroll
        for (int dt = 0; dt < 4; ++dt) {
            const __bf16* vr = vt + ((size_t)h * HD + dt * 16 + l15) * S + t0 + g * 8;
            acc[dt] = MFMA16(pa, *(const bf16x8*)vr, acc[dt]);
        }
    }

#pragma unroll
    for (int dt = 0; dt < 4; ++dt)
#pragma unroll
        for (int r = 0; r < 4; ++r)
            atomicAdd(&attn[(size_t)(r0 + r) * E + h * HD + dt * 16 + l15], acc[dt][r]);
}

// ---------------------------------------------------------------------------
extern "C" void kernel_launch(void* const* d_in, const int* in_sizes, int n_in,
                              void* d_out, int out_size, void* d_ws, size_t ws_size,
                              hipStream_t stream) {
    (void)in_sizes; (void)n_in; (void)out_size; (void)ws_size;
    const float* query = (const float*)d_in[0];
    const float* key   = (const float*)d_in[1];
    const float* value = (const float*)d_in[2];
    const float* sim   = (const float*)d_in[3];
    const float* Wq = (const float*)d_in[4];
    const float* bq = (const float*)d_in[5];
    const float* Wk = (const float*)d_in[6];
    const float* bk = (const float*)d_in[7];
    const float* Wv = (const float*)d_in[8];
    const float* bv = (const float*)d_in[9];
    const float* Wo = (const float*)d_in[10];
    const float* bo = (const float*)d_in[11];

    char* ws = (char*)d_ws;
    __bf16* q_bf  = (__bf16*)(ws);                  // 4 MB  [H][S][64] (pre-scaled 1/8)
    __bf16* k_bf  = (__bf16*)(ws + (4u << 20));     // 4 MB  [H][S][64]
    __bf16* v_bf  = (__bf16*)(ws + (8u << 20));     // 4 MB  [H][S][64]
    __bf16* vt_bf = (__bf16*)(ws + (12u << 20));    // 4 MB  [H][HD][S]
    float*  rel   = (float*) (ws + (16u << 20));    // 16 MB [S][S] (pre-scaled 1/8)
    float*  attn_f = (float*)(ws + (32u << 20));    // 8 MB  [S][E]
    float*  pst   = (float*) (ws + (40u << 20));    // 512 KB [NC][H][S]
    float*  rinv  = (float*) (ws + (41u << 20));    // 128 KB [H][S]

    float* out_f = (float*)d_out;                   // [S][E]
    float* w_out = out_f + (size_t)S * E;           // [H][S][S]

    hipMemsetAsync(attn_f, 0, (size_t)S * E * sizeof(float), stream);
    k_rel<<<dim3(16, 16), dim3(256), 0, stream>>>(sim, rel);
    k_gemm_qkv<<<dim3(8, 16, 3), dim3(256), 0, stream>>>(
        query, key, value, Wq, Wk, Wv, bq, bk, bv, q_bf, k_bf, v_bf);
    k_tr_v<<<dim3(S / 64, H), dim3(256), 0, stream>>>(v_bf, vt_bf);
    k_stats<<<dim3(S / 64, H, NC), dim3(256), 0, stream>>>(q_bf, k_bf, rel, pst);
    k_combine<<<dim3(H * S / 256), dim3(256), 0, stream>>>(pst, rinv);
    k_emit<<<dim3(S / 64, H, NC), dim3(256), 0, stream>>>(q_bf, k_bf, vt_bf, rel, rinv,
                                                          w_out, attn_f);
    k_gemm_out<<<dim3(8, 16, 1), dim3(256), 0, stream>>>(attn_f, Wo, bo, out_f);
}